// Round 3
// baseline (725.265 us; speedup 1.0000x reference)
//
#include <hip/hip_runtime.h>

#define T_TOK 4096
#define H_DIM 1024
#define F_DIM 2816
#define E_NUM 8
#define EPSV 1e-5f

typedef unsigned short u16;
typedef __attribute__((ext_vector_type(8))) short bf16x8;
typedef __attribute__((ext_vector_type(16))) float f32x16;
typedef __attribute__((ext_vector_type(8))) u16 u16x8;

__device__ __forceinline__ u16 f2bf(float f) {
  union { float f; unsigned u; } c; c.f = f;
  unsigned u = c.u;
  return (u16)((u + 0x7FFFu + ((u >> 16) & 1u)) >> 16);
}

// async 16B global->LDS; LDS dest is wave-uniform base + lane*16
__device__ __forceinline__ void llds16(const u16* g, u16* l) {
  __builtin_amdgcn_global_load_lds(
      (const __attribute__((address_space(1))) unsigned int*)g,
      (__attribute__((address_space(3))) unsigned int*)l, 16, 0, 0);
}

// ---------------- Router: RMSNorm + logits + softmax + top2 + gather lists ---
__global__ __launch_bounds__(256) void router_kernel(
    const float* __restrict__ hs, const float* __restrict__ lnw,
    const float* __restrict__ rw, u16* __restrict__ x_h,
    int* __restrict__ cnt, int* __restrict__ list,
    float* __restrict__ wcomb) {
  const int wave = threadIdx.x >> 6;
  const int lane = threadIdx.x & 63;
  const int t = blockIdx.x * 4 + wave;
  const float* row = hs + (size_t)t * H_DIM;

  float4 v[4];
  float ss = 0.f;
#pragma unroll
  for (int j = 0; j < 4; ++j) {
    v[j] = ((const float4*)row)[j * 64 + lane];
    ss += v[j].x * v[j].x + v[j].y * v[j].y + v[j].z * v[j].z + v[j].w * v[j].w;
  }
#pragma unroll
  for (int m = 32; m; m >>= 1) ss += __shfl_xor(ss, m, 64);
  const float inv = rsqrtf(ss * (1.0f / H_DIM) + EPSV);

  float lg[E_NUM];
#pragma unroll
  for (int e = 0; e < E_NUM; ++e) lg[e] = 0.f;

#pragma unroll
  for (int j = 0; j < 4; ++j) {
    const int idx = j * 64 + lane;
    const int h0 = idx * 4;
    float4 w4 = ((const float4*)lnw)[idx];
    float xv[4] = {v[j].x * inv * w4.x, v[j].y * inv * w4.y,
                   v[j].z * inv * w4.z, v[j].w * inv * w4.w};
    ushort4 xs;
    xs.x = f2bf(xv[0]); xs.y = f2bf(xv[1]); xs.z = f2bf(xv[2]); xs.w = f2bf(xv[3]);
    ((ushort4*)(x_h + (size_t)t * H_DIM))[idx] = xs;
#pragma unroll
    for (int q = 0; q < 4; ++q) {
      const float* rr = rw + (size_t)(h0 + q) * E_NUM;
      float4 a = ((const float4*)rr)[0];
      float4 b = ((const float4*)rr)[1];
      lg[0] += xv[q] * a.x; lg[1] += xv[q] * a.y;
      lg[2] += xv[q] * a.z; lg[3] += xv[q] * a.w;
      lg[4] += xv[q] * b.x; lg[5] += xv[q] * b.y;
      lg[6] += xv[q] * b.z; lg[7] += xv[q] * b.w;
    }
  }
#pragma unroll
  for (int e = 0; e < E_NUM; ++e)
#pragma unroll
    for (int m = 32; m; m >>= 1) lg[e] += __shfl_xor(lg[e], m, 64);

  if (lane == 0) {
    float mx = lg[0];
#pragma unroll
    for (int e = 1; e < E_NUM; ++e) mx = fmaxf(mx, lg[e]);
    float p[E_NUM], s = 0.f;
#pragma unroll
    for (int e = 0; e < E_NUM; ++e) { p[e] = __expf(lg[e] - mx); s += p[e]; }
    const float invs = 1.0f / s;
    int e1 = 0; float b1 = p[0];
#pragma unroll
    for (int e = 1; e < E_NUM; ++e) if (p[e] > b1) { b1 = p[e]; e1 = e; }
    int e2 = -1; float b2 = -1.f;
#pragma unroll
    for (int e = 0; e < E_NUM; ++e) if (e != e1 && p[e] > b2) { b2 = p[e]; e2 = e; }
    b1 *= invs; b2 *= invs;
    int p1 = atomicAdd(&cnt[e1], 1);
    list[e1 * T_TOK + p1] = t; wcomb[e1 * T_TOK + p1] = b1;
    int p2 = atomicAdd(&cnt[e2], 1);
    list[e2 * T_TOK + p2] = t; wcomb[e2 * T_TOK + p2] = b2;
  }
}

__global__ void offsets_kernel(const int* __restrict__ cnt, int* __restrict__ offs) {
  if (threadIdx.x == 0) {
    int s = 0;
    for (int e = 0; e < E_NUM; ++e) { offs[e] = s; s += cnt[e]; }
  }
}

// ------- Fused transpose-convert: all 3 weight tensors, 64x64 fp32 tiles -----
// wg/wu: [E][1024][2816] -> [E][2816][1024] bf16 ; wd: [E][2816][1024] -> [E][1024][2816]
__global__ __launch_bounds__(256) void transpose_fused(
    const float* __restrict__ wg, const float* __restrict__ wu,
    const float* __restrict__ wd, u16* __restrict__ wgT,
    u16* __restrict__ wuT, u16* __restrict__ wdT) {
  __shared__ float tile[64 * 65];
  const int bid = blockIdx.x;
  const int seg = bid / 5632;          // 0=wg, 1=wu, 2=wd
  const int rem = bid - seg * 5632;
  const int e = rem / 704;
  const int tt = rem - e * 704;
  int R, C, rt, ct;
  const float* in; u16* outp;
  if (seg < 2) {
    R = H_DIM; C = F_DIM; rt = tt / 44; ct = tt - rt * 44;
    in = seg ? wu : wg; outp = seg ? wuT : wgT;
  } else {
    R = F_DIM; C = H_DIM; rt = tt / 16; ct = tt - rt * 16;
    in = wd; outp = wdT;
  }
  const size_t base = (size_t)e * R * C;
  const int r0 = rt * 64, c0 = ct * 64;
  const int tid = threadIdx.x;
  const int rr = tid >> 4, cv = tid & 15;
#pragma unroll
  for (int p = 0; p < 4; ++p) {
    int r = p * 16 + rr;
    float4 v = *(const float4*)(in + base + (size_t)(r0 + r) * C + c0 + cv * 4);
    tile[r * 65 + cv * 4 + 0] = v.x;
    tile[r * 65 + cv * 4 + 1] = v.y;
    tile[r * 65 + cv * 4 + 2] = v.z;
    tile[r * 65 + cv * 4 + 3] = v.w;
  }
  __syncthreads();
#pragma unroll
  for (int q = 0; q < 2; ++q) {
    int id = q * 256 + tid;
    int c = id >> 3, rc = id & 7;
    u16x8 o;
#pragma unroll
    for (int j = 0; j < 8; ++j) o[j] = f2bf(tile[(rc * 8 + j) * 65 + c]);
    *(u16x8*)(outp + base + (size_t)(c0 + c) * R + r0 + rc * 8) = o;
  }
}

// ---------------- Stage 1: h = silu(X Wg) * (X Wu) --- 128x128-dual, 32x32x16
// LDS: row-major [row][64] u16; 16B chunk c of row r at phys chunk c^(r&7).
__global__ __launch_bounds__(256) void gemm1_kernel(
    const u16* __restrict__ x_h, const u16* __restrict__ wgT,
    const u16* __restrict__ wuT, const int* __restrict__ cnt,
    const int* __restrict__ offs, const int* __restrict__ list,
    u16* __restrict__ hbuf) {
  const int e = blockIdx.z;
  const int n_e = cnt[e];
  const int rt = blockIdx.y;
  if (rt * 128 >= n_e) return;
  const int ft = blockIdx.x;

  __shared__ __align__(16) u16 As[128 * 64];
  __shared__ __align__(16) u16 Bgs[128 * 64];
  __shared__ __align__(16) u16 Bus[128 * 64];
  __shared__ int tok[128];

  const int tid = threadIdx.x;
  if (tid < 128) {
    int r = rt * 128 + tid;
    if (r >= n_e) r = n_e - 1;
    tok[tid] = list[e * T_TOK + r];
  }
  __syncthreads();

  const int wv = tid >> 6, lane = tid & 63;
  const int wm = wv >> 1, wn = wv & 1;
  const int l31 = lane & 31, kh = lane >> 5, l7 = lane & 7;
  const int sr = lane >> 3;
  const int sw = (l7 ^ sr) << 3;   // swizzled source chunk offset (u16)

  const size_t wb = ((size_t)e * F_DIM + (size_t)ft * 128) * H_DIM;
  const u16* agp[4]; const u16* bgp[4]; const u16* bup[4];
#pragma unroll
  for (int i = 0; i < 4; ++i) {
    int r = wv * 32 + i * 8 + sr;
    agp[i] = x_h + (size_t)tok[r] * H_DIM + sw;
    bgp[i] = wgT + wb + (size_t)r * H_DIM + sw;
    bup[i] = wuT + wb + (size_t)r * H_DIM + sw;
  }

  int arow[2], brow[2];
#pragma unroll
  for (int t = 0; t < 2; ++t) {
    arow[t] = (wm * 64 + t * 32 + l31) * 64;
    brow[t] = (wn * 64 + t * 32 + l31) * 64;
  }

  f32x16 accg[2][2], accu[2][2];
#pragma unroll
  for (int i = 0; i < 2; ++i)
#pragma unroll
    for (int j = 0; j < 2; ++j) {
      accg[i][j] = (f32x16)(0.f);
      accu[i][j] = (f32x16)(0.f);
    }

  for (int k0 = 0; k0 < H_DIM; k0 += 64) {
#pragma unroll
    for (int i = 0; i < 4; ++i) {
      llds16(agp[i] + k0, &As[(wv * 32 + i * 8) * 64]);
      llds16(bgp[i] + k0, &Bgs[(wv * 32 + i * 8) * 64]);
      llds16(bup[i] + k0, &Bus[(wv * 32 + i * 8) * 64]);
    }
    __syncthreads();
#pragma unroll
    for (int ks = 0; ks < 4; ++ks) {
      const int cho = (((ks * 2) | kh) ^ l7) << 3;
      bf16x8 a[2], bg[2], bu[2];
#pragma unroll
      for (int t = 0; t < 2; ++t) {
        a[t]  = *(const bf16x8*)&As [arow[t] + cho];
        bg[t] = *(const bf16x8*)&Bgs[brow[t] + cho];
        bu[t] = *(const bf16x8*)&Bus[brow[t] + cho];
      }
#pragma unroll
      for (int tm = 0; tm < 2; ++tm)
#pragma unroll
        for (int tn = 0; tn < 2; ++tn) {
          accg[tm][tn] = __builtin_amdgcn_mfma_f32_32x32x16_bf16(a[tm], bg[tn], accg[tm][tn], 0, 0, 0);
          accu[tm][tn] = __builtin_amdgcn_mfma_f32_32x32x16_bf16(a[tm], bu[tn], accu[tm][tn], 0, 0, 0);
        }
    }
    __syncthreads();
  }

  const int oe = offs[e];
#pragma unroll
  for (int tm = 0; tm < 2; ++tm)
#pragma unroll
    for (int rg = 0; rg < 16; ++rg) {
      const int rowi = (rg & 3) + 8 * (rg >> 2) + 4 * kh;
      const int gr = rt * 128 + wm * 64 + tm * 32 + rowi;
      if (gr < n_e) {
        const size_t ob = (size_t)(oe + gr) * F_DIM + ft * 128 + wn * 64 + l31;
#pragma unroll
        for (int tn = 0; tn < 2; ++tn) {
          float g = accg[tm][tn][rg];
          float u = accu[tm][tn][rg];
          float hv = g / (1.0f + __expf(-g)) * u;
          hbuf[ob + tn * 32] = f2bf(hv);
        }
      }
    }
}

// ------- Stage 2: out[t] += cw * (h Wd) --- 128x128, 32x32x16, atomic epilogue
__global__ __launch_bounds__(256) void gemm2_kernel(
    const u16* __restrict__ hbuf, const u16* __restrict__ wdT,
    const int* __restrict__ cnt, const int* __restrict__ offs,
    const int* __restrict__ list, const float* __restrict__ wcomb,
    float* __restrict__ out) {
  const int e = blockIdx.z;
  const int n_e = cnt[e];
  const int rt = blockIdx.y;
  if (rt * 128 >= n_e) return;
  const int nt = blockIdx.x;

  __shared__ __align__(16) u16 As[128 * 64];
  __shared__ __align__(16) u16 Bs[128 * 64];
  __shared__ int hrow[128];

  const int tid = threadIdx.x;
  const int oe = offs[e];
  if (tid < 128) {
    int r = rt * 128 + tid;
    if (r >= n_e) r = n_e - 1;
    hrow[tid] = oe + r;
  }
  __syncthreads();

  const int wv = tid >> 6, lane = tid & 63;
  const int wm = wv >> 1, wn = wv & 1;
  const int l31 = lane & 31, kh = lane >> 5, l7 = lane & 7;
  const int sr = lane >> 3;
  const int sw = (l7 ^ sr) << 3;

  const size_t wb = ((size_t)e * H_DIM + (size_t)nt * 128) * F_DIM;
  const u16* agp[4]; const u16* bgp[4];
#pragma unroll
  for (int i = 0; i < 4; ++i) {
    int r = wv * 32 + i * 8 + sr;
    agp[i] = hbuf + (size_t)hrow[r] * F_DIM + sw;
    bgp[i] = wdT + wb + (size_t)r * F_DIM + sw;
  }

  int arow[2], brow[2];
#pragma unroll
  for (int t = 0; t < 2; ++t) {
    arow[t] = (wm * 64 + t * 32 + l31) * 64;
    brow[t] = (wn * 64 + t * 32 + l31) * 64;
  }

  f32x16 acc[2][2];
#pragma unroll
  for (int i = 0; i < 2; ++i)
#pragma unroll
    for (int j = 0; j < 2; ++j) acc[i][j] = (f32x16)(0.f);

  for (int k0 = 0; k0 < F_DIM; k0 += 64) {
#pragma unroll
    for (int i = 0; i < 4; ++i) {
      llds16(agp[i] + k0, &As[(wv * 32 + i * 8) * 64]);
      llds16(bgp[i] + k0, &Bs[(wv * 32 + i * 8) * 64]);
    }
    __syncthreads();
#pragma unroll
    for (int ks = 0; ks < 4; ++ks) {
      const int cho = (((ks * 2) | kh) ^ l7) << 3;
      bf16x8 a[2], b[2];
#pragma unroll
      for (int t = 0; t < 2; ++t) {
        a[t] = *(const bf16x8*)&As[arow[t] + cho];
        b[t] = *(const bf16x8*)&Bs[brow[t] + cho];
      }
#pragma unroll
      for (int tm = 0; tm < 2; ++tm)
#pragma unroll
        for (int tn = 0; tn < 2; ++tn)
          acc[tm][tn] = __builtin_amdgcn_mfma_f32_32x32x16_bf16(a[tm], b[tn], acc[tm][tn], 0, 0, 0);
    }
    __syncthreads();
  }

#pragma unroll
  for (int tm = 0; tm < 2; ++tm)
#pragma unroll
    for (int rg = 0; rg < 16; ++rg) {
      const int rowi = (rg & 3) + 8 * (rg >> 2) + 4 * kh;
      const int gr = rt * 128 + wm * 64 + tm * 32 + rowi;
      if (gr < n_e) {
        const int t = list[e * T_TOK + gr];
        const float cw = wcomb[e * T_TOK + gr];
        float* ob = out + (size_t)t * H_DIM + nt * 128 + wn * 64 + l31;
#pragma unroll
        for (int tn = 0; tn < 2; ++tn)
          atomicAdd(ob + tn * 32, acc[tm][tn][rg] * cw);
      }
    }
}

extern "C" void kernel_launch(void* const* d_in, const int* in_sizes, int n_in,
                              void* d_out, int out_size, void* d_ws, size_t ws_size,
                              hipStream_t stream) {
  const float* hs  = (const float*)d_in[0];
  const float* lnw = (const float*)d_in[1];
  const float* rw  = (const float*)d_in[2];
  const float* wg  = (const float*)d_in[3];
  const float* wu  = (const float*)d_in[4];
  const float* wd  = (const float*)d_in[5];
  float* out = (float*)d_out;

  char* p = (char*)d_ws;
  const size_t SZ_XH = (size_t)T_TOK * H_DIM * 2;          // 8 MB
  const size_t SZ_W  = (size_t)E_NUM * F_DIM * H_DIM * 2;  // 46 MB each
  const size_t SZ_HB = (size_t)T_TOK * 2 * F_DIM * 2;      // 46 MB

  u16* x_h  = (u16*)p;   p += SZ_XH;
  u16* wgT  = (u16*)p;   p += SZ_W;
  u16* wuT  = (u16*)p;   p += SZ_W;
  u16* wdT  = (u16*)p;   p += SZ_W;
  u16* hbuf = (u16*)p;   p += SZ_HB;
  int* cnt  = (int*)p;   p += 256;
  int* offs = (int*)p;   p += 256;
  int* list = (int*)p;   p += (size_t)E_NUM * T_TOK * 4;
  float* wcomb = (float*)p; p += (size_t)E_NUM * T_TOK * 4;

  hipMemsetAsync(cnt, 0, 256, stream);
  hipMemsetAsync(out, 0, (size_t)out_size * 4, stream);
  router_kernel<<<T_TOK / 4, 256, 0, stream>>>(hs, lnw, rw, x_h, cnt, list, wcomb);
  offsets_kernel<<<1, 64, 0, stream>>>(cnt, offs);
  transpose_fused<<<3 * 5632, 256, 0, stream>>>(wg, wu, wd, wgT, wuT, wdT);
  gemm1_kernel<<<dim3(F_DIM / 128, T_TOK / 128, E_NUM), 256, 0, stream>>>(x_h, wgT, wuT, cnt, offs, list, hbuf);
  gemm2_kernel<<<dim3(H_DIM / 128, T_TOK / 128, E_NUM), 256, 0, stream>>>(hbuf, wdT, cnt, offs, list, wcomb, out);
}

// Round 4
// 686.430 us; speedup vs baseline: 1.0566x; 1.0566x over previous
//
#include <hip/hip_runtime.h>

#define T_TOK 4096
#define H_DIM 1024
#define F_DIM 2816
#define E_NUM 8
#define EPSV 1e-5f

typedef unsigned short u16;
typedef __attribute__((ext_vector_type(8))) short bf16x8;
typedef __attribute__((ext_vector_type(16))) float f32x16;
typedef __attribute__((ext_vector_type(8))) u16 u16x8;

__device__ __forceinline__ u16 f2bf(float f) {
  union { float f; unsigned u; } c; c.f = f;
  unsigned u = c.u;
  return (u16)((u + 0x7FFFu + ((u >> 16) & 1u)) >> 16);
}
__device__ __forceinline__ float bf2f(u16 h) {
  union { unsigned u; float f; } c; c.u = (unsigned)h << 16;
  return c.f;
}

// async 16B global->LDS; LDS dest is wave-uniform base + lane*16
__device__ __forceinline__ void llds16(const u16* g, u16* l) {
  __builtin_amdgcn_global_load_lds(
      (const __attribute__((address_space(1))) unsigned int*)g,
      (__attribute__((address_space(3))) unsigned int*)l, 16, 0, 0);
}

// ---------------- Router: RMSNorm + logits + softmax + top2 + gather lists ---
__global__ __launch_bounds__(256) void router_kernel(
    const float* __restrict__ hs, const float* __restrict__ lnw,
    const float* __restrict__ rw, u16* __restrict__ x_h,
    int* __restrict__ cnt, int* __restrict__ list,
    float* __restrict__ wcomb, int* __restrict__ slot) {
  const int wave = threadIdx.x >> 6;
  const int lane = threadIdx.x & 63;
  const int t = blockIdx.x * 4 + wave;
  const float* row = hs + (size_t)t * H_DIM;

  float4 v[4];
  float ss = 0.f;
#pragma unroll
  for (int j = 0; j < 4; ++j) {
    v[j] = ((const float4*)row)[j * 64 + lane];
    ss += v[j].x * v[j].x + v[j].y * v[j].y + v[j].z * v[j].z + v[j].w * v[j].w;
  }
#pragma unroll
  for (int m = 32; m; m >>= 1) ss += __shfl_xor(ss, m, 64);
  const float inv = rsqrtf(ss * (1.0f / H_DIM) + EPSV);

  float lg[E_NUM];
#pragma unroll
  for (int e = 0; e < E_NUM; ++e) lg[e] = 0.f;

#pragma unroll
  for (int j = 0; j < 4; ++j) {
    const int idx = j * 64 + lane;
    const int h0 = idx * 4;
    float4 w4 = ((const float4*)lnw)[idx];
    float xv[4] = {v[j].x * inv * w4.x, v[j].y * inv * w4.y,
                   v[j].z * inv * w4.z, v[j].w * inv * w4.w};
    ushort4 xs;
    xs.x = f2bf(xv[0]); xs.y = f2bf(xv[1]); xs.z = f2bf(xv[2]); xs.w = f2bf(xv[3]);
    ((ushort4*)(x_h + (size_t)t * H_DIM))[idx] = xs;
#pragma unroll
    for (int q = 0; q < 4; ++q) {
      const float* rr = rw + (size_t)(h0 + q) * E_NUM;
      float4 a = ((const float4*)rr)[0];
      float4 b = ((const float4*)rr)[1];
      lg[0] += xv[q] * a.x; lg[1] += xv[q] * a.y;
      lg[2] += xv[q] * a.z; lg[3] += xv[q] * a.w;
      lg[4] += xv[q] * b.x; lg[5] += xv[q] * b.y;
      lg[6] += xv[q] * b.z; lg[7] += xv[q] * b.w;
    }
  }
#pragma unroll
  for (int e = 0; e < E_NUM; ++e)
#pragma unroll
    for (int m = 32; m; m >>= 1) lg[e] += __shfl_xor(lg[e], m, 64);

  if (lane == 0) {
    float mx = lg[0];
#pragma unroll
    for (int e = 1; e < E_NUM; ++e) mx = fmaxf(mx, lg[e]);
    float p[E_NUM], s = 0.f;
#pragma unroll
    for (int e = 0; e < E_NUM; ++e) { p[e] = __expf(lg[e] - mx); s += p[e]; }
    const float invs = 1.0f / s;
    int e1 = 0; float b1 = p[0];
#pragma unroll
    for (int e = 1; e < E_NUM; ++e) if (p[e] > b1) { b1 = p[e]; e1 = e; }
    int e2 = -1; float b2 = -1.f;
#pragma unroll
    for (int e = 0; e < E_NUM; ++e) if (e != e1 && p[e] > b2) { b2 = p[e]; e2 = e; }
    b1 *= invs; b2 *= invs;
    int p1 = atomicAdd(&cnt[e1], 1);
    list[e1 * T_TOK + p1] = t; wcomb[e1 * T_TOK + p1] = b1;
    slot[2 * t] = (e1 << 16) | p1;
    int p2 = atomicAdd(&cnt[e2], 1);
    list[e2 * T_TOK + p2] = t; wcomb[e2 * T_TOK + p2] = b2;
    slot[2 * t + 1] = (e2 << 16) | p2;
  }
}

__global__ void offsets_kernel(const int* __restrict__ cnt, int* __restrict__ offs) {
  if (threadIdx.x == 0) {
    int s = 0;
    for (int e = 0; e < E_NUM; ++e) { offs[e] = s; s += cnt[e]; }
  }
}

// ------- Fused transpose-convert: all 3 weight tensors, 64x64 fp32 tiles -----
__global__ __launch_bounds__(256) void transpose_fused(
    const float* __restrict__ wg, const float* __restrict__ wu,
    const float* __restrict__ wd, u16* __restrict__ wgT,
    u16* __restrict__ wuT, u16* __restrict__ wdT) {
  __shared__ float tile[64 * 65];
  const int bid = blockIdx.x;
  const int seg = bid / 5632;          // 0=wg, 1=wu, 2=wd
  const int rem = bid - seg * 5632;
  const int e = rem / 704;
  const int tt = rem - e * 704;
  int R, C, rt, ct;
  const float* in; u16* outp;
  if (seg < 2) {
    R = H_DIM; C = F_DIM; rt = tt / 44; ct = tt - rt * 44;
    in = seg ? wu : wg; outp = seg ? wuT : wgT;
  } else {
    R = F_DIM; C = H_DIM; rt = tt / 16; ct = tt - rt * 16;
    in = wd; outp = wdT;
  }
  const size_t base = (size_t)e * R * C;
  const int r0 = rt * 64, c0 = ct * 64;
  const int tid = threadIdx.x;
  const int rr = tid >> 4, cv = tid & 15;
#pragma unroll
  for (int p = 0; p < 4; ++p) {
    int r = p * 16 + rr;
    float4 v = *(const float4*)(in + base + (size_t)(r0 + r) * C + c0 + cv * 4);
    tile[r * 65 + cv * 4 + 0] = v.x;
    tile[r * 65 + cv * 4 + 1] = v.y;
    tile[r * 65 + cv * 4 + 2] = v.z;
    tile[r * 65 + cv * 4 + 3] = v.w;
  }
  __syncthreads();
#pragma unroll
  for (int q = 0; q < 2; ++q) {
    int id = q * 256 + tid;
    int c = id >> 3, rc = id & 7;
    u16x8 o;
#pragma unroll
    for (int j = 0; j < 8; ++j) o[j] = f2bf(tile[(rc * 8 + j) * 65 + c]);
    *(u16x8*)(outp + base + (size_t)(c0 + c) * R + r0 + rc * 8) = o;
  }
}

// -------- Stage 1 pass: 128x128, 32x32x16, Tm=Tn=2 (64 AGPR) -----------------
// fuse=0: outb = bf16(acc)   (gate pass)
// fuse=1: outb = bf16(silu(gin)*acc)   (up pass, reads gate from gin)
// LDS: [row][64] u16; logical 16B chunk c of row r at phys chunk c^(r&7).
__global__ __launch_bounds__(256, 3) void gemm1_pass(
    const u16* __restrict__ xs, const u16* __restrict__ wT,
    const u16* __restrict__ gin, const int* __restrict__ cnt,
    const int* __restrict__ offs, const int* __restrict__ list,
    u16* __restrict__ outb, int fuse) {
  const int e = blockIdx.z;
  const int n_e = cnt[e];
  const int rt = blockIdx.y;
  if (rt * 128 >= n_e) return;
  const int ft = blockIdx.x;

  __shared__ __align__(16) u16 As[128 * 64];
  __shared__ __align__(16) u16 Bs[128 * 64];
  __shared__ int tok[128];

  const int tid = threadIdx.x;
  if (tid < 128) {
    int r = rt * 128 + tid;
    if (r >= n_e) r = n_e - 1;
    tok[tid] = list[e * T_TOK + r];
  }
  __syncthreads();

  const int wv = tid >> 6, lane = tid & 63;
  const int wm = wv >> 1, wn = wv & 1;
  const int l31 = lane & 31, kh = lane >> 5, l7 = lane & 7;
  const int sr = lane >> 3;
  const int sw = (l7 ^ sr) << 3;

  const size_t wb = ((size_t)e * F_DIM + (size_t)ft * 128) * H_DIM;
  const u16* agp[4]; const u16* bgp[4];
#pragma unroll
  for (int i = 0; i < 4; ++i) {
    int r = wv * 32 + i * 8 + sr;
    agp[i] = xs + (size_t)tok[r] * H_DIM + sw;
    bgp[i] = wT + wb + (size_t)r * H_DIM + sw;
  }

  int arow[2], brow[2];
#pragma unroll
  for (int t = 0; t < 2; ++t) {
    arow[t] = (wm * 64 + t * 32 + l31) * 64;
    brow[t] = (wn * 64 + t * 32 + l31) * 64;
  }

  f32x16 acc[2][2];
#pragma unroll
  for (int i = 0; i < 2; ++i)
#pragma unroll
    for (int j = 0; j < 2; ++j) acc[i][j] = (f32x16)(0.f);

  for (int k0 = 0; k0 < H_DIM; k0 += 64) {
#pragma unroll
    for (int i = 0; i < 4; ++i) {
      llds16(agp[i] + k0, &As[(wv * 32 + i * 8) * 64]);
      llds16(bgp[i] + k0, &Bs[(wv * 32 + i * 8) * 64]);
    }
    __syncthreads();
#pragma unroll
    for (int ks = 0; ks < 4; ++ks) {
      const int cho = (((ks * 2) | kh) ^ l7) << 3;
      bf16x8 a[2], b[2];
#pragma unroll
      for (int t = 0; t < 2; ++t) {
        a[t] = *(const bf16x8*)&As[arow[t] + cho];
        b[t] = *(const bf16x8*)&Bs[brow[t] + cho];
      }
#pragma unroll
      for (int tm = 0; tm < 2; ++tm)
#pragma unroll
        for (int tn = 0; tn < 2; ++tn)
          acc[tm][tn] = __builtin_amdgcn_mfma_f32_32x32x16_bf16(a[tm], b[tn], acc[tm][tn], 0, 0, 0);
    }
    __syncthreads();
  }

  const int oe = offs[e];
#pragma unroll
  for (int tm = 0; tm < 2; ++tm)
#pragma unroll
    for (int rg = 0; rg < 16; ++rg) {
      const int rowi = (rg & 3) + 8 * (rg >> 2) + 4 * kh;
      const int gr = rt * 128 + wm * 64 + tm * 32 + rowi;
      if (gr < n_e) {
        const size_t ob = (size_t)(oe + gr) * F_DIM + ft * 128 + wn * 64 + l31;
#pragma unroll
        for (int tn = 0; tn < 2; ++tn) {
          float v = acc[tm][tn][rg];
          if (fuse) {
            float g = bf2f(gin[ob + tn * 32]);
            v = g / (1.0f + __expf(-g)) * v;
          }
          outb[ob + tn * 32] = f2bf(v);
        }
      }
    }
}

// -------- Stage 2: contrib = cw * (h Wd), 128x128, 32x32x16, Tm=Tn=2 ---------
__global__ __launch_bounds__(256, 3) void gemm2_kernel(
    const u16* __restrict__ hbuf, const u16* __restrict__ wdT,
    const int* __restrict__ cnt, const int* __restrict__ offs,
    const float* __restrict__ wcomb, float* __restrict__ contrib) {
  const int e = blockIdx.z;
  const int n_e = cnt[e];
  const int rt = blockIdx.y;
  if (rt * 128 >= n_e) return;
  const int nt = blockIdx.x;

  __shared__ __align__(16) u16 As[128 * 64];
  __shared__ __align__(16) u16 Bs[128 * 64];
  __shared__ int hrow[128];

  const int tid = threadIdx.x;
  const int oe = offs[e];
  if (tid < 128) {
    int r = rt * 128 + tid;
    if (r >= n_e) r = n_e - 1;
    hrow[tid] = oe + r;
  }
  __syncthreads();

  const int wv = tid >> 6, lane = tid & 63;
  const int wm = wv >> 1, wn = wv & 1;
  const int l31 = lane & 31, kh = lane >> 5, l7 = lane & 7;
  const int sr = lane >> 3;
  const int sw = (l7 ^ sr) << 3;

  const size_t wb = ((size_t)e * H_DIM + (size_t)nt * 128) * F_DIM;
  const u16* agp[4]; const u16* bgp[4];
#pragma unroll
  for (int i = 0; i < 4; ++i) {
    int r = wv * 32 + i * 8 + sr;
    agp[i] = hbuf + (size_t)hrow[r] * F_DIM + sw;
    bgp[i] = wdT + wb + (size_t)r * F_DIM + sw;
  }

  int arow[2], brow[2];
#pragma unroll
  for (int t = 0; t < 2; ++t) {
    arow[t] = (wm * 64 + t * 32 + l31) * 64;
    brow[t] = (wn * 64 + t * 32 + l31) * 64;
  }

  f32x16 acc[2][2];
#pragma unroll
  for (int i = 0; i < 2; ++i)
#pragma unroll
    for (int j = 0; j < 2; ++j) acc[i][j] = (f32x16)(0.f);

  for (int k0 = 0; k0 < F_DIM; k0 += 64) {
#pragma unroll
    for (int i = 0; i < 4; ++i) {
      llds16(agp[i] + k0, &As[(wv * 32 + i * 8) * 64]);
      llds16(bgp[i] + k0, &Bs[(wv * 32 + i * 8) * 64]);
    }
    __syncthreads();
#pragma unroll
    for (int ks = 0; ks < 4; ++ks) {
      const int cho = (((ks * 2) | kh) ^ l7) << 3;
      bf16x8 a[2], b[2];
#pragma unroll
      for (int t = 0; t < 2; ++t) {
        a[t] = *(const bf16x8*)&As[arow[t] + cho];
        b[t] = *(const bf16x8*)&Bs[brow[t] + cho];
      }
#pragma unroll
      for (int tm = 0; tm < 2; ++tm)
#pragma unroll
        for (int tn = 0; tn < 2; ++tn)
          acc[tm][tn] = __builtin_amdgcn_mfma_f32_32x32x16_bf16(a[tm], b[tn], acc[tm][tn], 0, 0, 0);
    }
    __syncthreads();
  }

#pragma unroll
  for (int tm = 0; tm < 2; ++tm)
#pragma unroll
    for (int rg = 0; rg < 16; ++rg) {
      const int rowi = (rg & 3) + 8 * (rg >> 2) + 4 * kh;
      const int gr = rt * 128 + wm * 64 + tm * 32 + rowi;
      if (gr < n_e) {
        const float cw = wcomb[e * T_TOK + gr];
        const size_t ob = (size_t)(oe + gr) * H_DIM + nt * 128 + wn * 64 + l31;
#pragma unroll
        for (int tn = 0; tn < 2; ++tn)
          contrib[ob + tn * 32] = acc[tm][tn][rg] * cw;
      }
    }
}

// ---------------- Combine: out[t] = contrib[slot0] + contrib[slot1] ----------
__global__ __launch_bounds__(256) void combine_kernel(
    const float* __restrict__ contrib, const int* __restrict__ offs,
    const int* __restrict__ slot, float* __restrict__ out) {
  const int t = blockIdx.x;
  const int s0 = slot[2 * t], s1 = slot[2 * t + 1];
  const int r0 = offs[s0 >> 16] + (s0 & 0xFFFF);
  const int r1 = offs[s1 >> 16] + (s1 & 0xFFFF);
  float4 a = ((const float4*)(contrib + (size_t)r0 * H_DIM))[threadIdx.x];
  float4 b = ((const float4*)(contrib + (size_t)r1 * H_DIM))[threadIdx.x];
  float4 o = {a.x + b.x, a.y + b.y, a.z + b.z, a.w + b.w};
  ((float4*)(out + (size_t)t * H_DIM))[threadIdx.x] = o;
}

extern "C" void kernel_launch(void* const* d_in, const int* in_sizes, int n_in,
                              void* d_out, int out_size, void* d_ws, size_t ws_size,
                              hipStream_t stream) {
  const float* hs  = (const float*)d_in[0];
  const float* lnw = (const float*)d_in[1];
  const float* rw  = (const float*)d_in[2];
  const float* wg  = (const float*)d_in[3];
  const float* wu  = (const float*)d_in[4];
  const float* wd  = (const float*)d_in[5];
  float* out = (float*)d_out;

  char* p = (char*)d_ws;
  const size_t SZ_XH = (size_t)T_TOK * H_DIM * 2;          // 8 MB
  const size_t SZ_W  = (size_t)E_NUM * F_DIM * H_DIM * 2;  // 46 MB each
  const size_t SZ_HB = (size_t)T_TOK * 2 * F_DIM * 2;      // 46 MB

  u16* x_h  = (u16*)p;   p += SZ_XH;
  u16* wgT  = (u16*)p;   p += SZ_W;
  u16* wuT  = (u16*)p;   p += SZ_W;
  u16* wdT  = (u16*)p;   p += SZ_W;
  u16* gbuf = (u16*)p;   p += SZ_HB;
  u16* hbuf = (u16*)p;   p += SZ_HB;
  int* cnt  = (int*)p;   p += 256;
  int* offs = (int*)p;   p += 256;
  int* list = (int*)p;   p += (size_t)E_NUM * T_TOK * 4;
  float* wcomb = (float*)p; p += (size_t)E_NUM * T_TOK * 4;
  int* slot = (int*)p;   p += (size_t)T_TOK * 2 * 4;
  // contrib aliases wgT (dead after the gate pass; gemm2 runs after gemm_up)
  float* contrib = (float*)wgT;   // 33.5 MB < 46 MB

  hipMemsetAsync(cnt, 0, 256, stream);
  router_kernel<<<T_TOK / 4, 256, 0, stream>>>(hs, lnw, rw, x_h, cnt, list, wcomb, slot);
  offsets_kernel<<<1, 64, 0, stream>>>(cnt, offs);
  transpose_fused<<<3 * 5632, 256, 0, stream>>>(wg, wu, wd, wgT, wuT, wdT);
  gemm1_pass<<<dim3(F_DIM / 128, T_TOK / 128, E_NUM), 256, 0, stream>>>(
      x_h, wgT, (const u16*)nullptr, cnt, offs, list, gbuf, 0);
  gemm1_pass<<<dim3(F_DIM / 128, T_TOK / 128, E_NUM), 256, 0, stream>>>(
      x_h, wuT, gbuf, cnt, offs, list, hbuf, 1);
  gemm2_kernel<<<dim3(H_DIM / 128, T_TOK / 128, E_NUM), 256, 0, stream>>>(
      hbuf, wdT, cnt, offs, wcomb, contrib);
  combine_kernel<<<T_TOK, 256, 0, stream>>>(contrib, offs, slot, out);
}